// Round 11
// baseline (184.701 us; speedup 1.0000x reference)
//
#include <hip/hip_runtime.h>
#include <hip/hip_bf16.h>

// B=2, S=2048, D=1024, H=16, DK=64, BAND=100. Inputs f32 (auto-detect; bf16 fallback).
// Output f32. 4 dispatches: convert_all (ballot detect) -> qkv_gemm (BK=64 swizzled)
// -> attn (single-pass softmax, XCD swizzle, band prestage) -> o_gemm (BK=32, R9 form).

typedef __attribute__((ext_vector_type(8))) short short8;
typedef __attribute__((ext_vector_type(4))) float f32x4;

#define S_LEN 2048
#define NH 16
#define DK 64
#define BANDW 100

#define X_ELEMS   (2 * S_LEN * 1024)
#define W_ELEMS   (1024 * 1024)
#define QKV_ELEMS (2 * NH * S_LEN * DK)
#define AO_ELEMS  (2 * S_LEN * 1024)

__device__ __attribute__((aligned(256))) short g_X[X_ELEMS];
__device__ __attribute__((aligned(256))) short g_W[4 * W_ELEMS];   // Wq|Wk|Wv|Wo
__device__ __attribute__((aligned(256))) short g_b[4 * 1024];      // bq|bk|bv|bo
__device__ __attribute__((aligned(256))) short g_Q[QKV_ELEMS];
__device__ __attribute__((aligned(256))) short g_K[QKV_ELEMS];
__device__ __attribute__((aligned(256))) short g_V[QKV_ELEMS];     // row-major [B,H,S,DK]
__device__ __attribute__((aligned(256))) short g_AO[AO_ELEMS];

__device__ __forceinline__ float bf2f(short u) {
    unsigned x = ((unsigned)(unsigned short)u) << 16;
    return __builtin_bit_cast(float, x);
}
__device__ __forceinline__ short f2bf(float f) {
    unsigned x = __builtin_bit_cast(unsigned, f);
    unsigned r = (x + 0x7fffu + ((x >> 16) & 1u)) >> 16;
    return (short)r;
}

#define GLOAD_LDS(gp, lp) \
    __builtin_amdgcn_global_load_lds( \
        (const __attribute__((address_space(1))) void*)(gp), \
        (__attribute__((address_space(3))) void*)(lp), 16, 0, 0)

// ---------------- Fused detect + convert (1 dispatch, all 9 tensors) ----------------
// Detect: per-wave ballot on "all 4 sampled low-shorts have sane bf16 exponents".
// bf16 data -> ~64/64 lanes true; f32 data (low short = mantissa bits) -> ~0/64.
#define XC   (X_ELEMS / 8)
#define WC   (W_ELEMS / 8)
#define BC   (1024 / 8)
#define TOTC (XC + 4 * WC + 4 * BC)

__global__ __launch_bounds__(256) void convert_all(
    const void* __restrict__ x,
    const void* __restrict__ w0, const void* __restrict__ b0,
    const void* __restrict__ w1, const void* __restrict__ b1,
    const void* __restrict__ w2, const void* __restrict__ b2,
    const void* __restrict__ w3, const void* __restrict__ b3)
{
    int local = 0;
    {
        const unsigned* xw = (const unsigned*)x;
        #pragma unroll
        for (int i = 0; i < 4; i++) {
            unsigned wv = xw[(threadIdx.x & 63) * 4 + i];
            unsigned e = (wv >> 7) & 0xFF;
            if (e >= 100 && e <= 140) local++;
        }
    }
    const int is_bf16 = (__popcll(__ballot(local == 4)) > 32);

    long i = (long)blockIdx.x * 256 + threadIdx.x;
    if (i >= TOTC) return;

    const void* src; short* dst; long off;
    if (i < XC)                { src = x;  dst = g_X;              off = i; }
    else if ((i -= XC) < WC)   { src = w0; dst = g_W + 0L*W_ELEMS; off = i; }
    else if ((i -= WC) < WC)   { src = w1; dst = g_W + 1L*W_ELEMS; off = i; }
    else if ((i -= WC) < WC)   { src = w2; dst = g_W + 2L*W_ELEMS; off = i; }
    else if ((i -= WC) < WC)   { src = w3; dst = g_W + 3L*W_ELEMS; off = i; }
    else if ((i -= WC) < BC)   { src = b0; dst = g_b + 0*1024;     off = i; }
    else if ((i -= BC) < BC)   { src = b1; dst = g_b + 1*1024;     off = i; }
    else if ((i -= BC) < BC)   { src = b2; dst = g_b + 2*1024;     off = i; }
    else                       { src = b3; dst = g_b + 3*1024;     off = i - BC; }

    if (is_bf16) {
        ((short8*)dst)[off] = ((const short8*)src)[off];
    } else {
        const float* s = (const float*)src + off * 8;
        short8 o;
        #pragma unroll
        for (int e = 0; e < 8; e++) o[e] = f2bf(s[e]);
        ((short8*)dst)[off] = o;
    }
}

// ------------- QKV GEMM: 128x128 tile, BK=64, XOR-swizzled LDS (0 conflicts) --------
// LDS phys: elem(row, seg) at row*64 + (seg ^ (row&7))*8; swizzle via global src addr.
// A/B frag: idx=lane&15, k=(lane>>4)*8+j ; C/D: col=lane&15, row=(lane>>4)*4+r
__global__ __launch_bounds__(256) void qkv_gemm()
{
    __shared__ __attribute__((aligned(16))) short As[128 * 64];
    __shared__ __attribute__((aligned(16))) short Bs[128 * 64];

    const int z = blockIdx.z;
    const short* __restrict__ X = g_X;
    const short* __restrict__ W = g_W + (long)z * W_ELEMS;
    const short* __restrict__ bias = g_b + z * 1024;
    short* __restrict__ Out = (z == 0) ? g_Q : ((z == 1) ? g_K : g_V);

    const int t = threadIdx.x;
    const int lane = t & 63;
    const int wid  = t >> 6;
    const int wm = wid & 1, wn = wid >> 1;
    const int l15 = lane & 15;
    const int g   = lane >> 4;
    const int mb = blockIdx.x * 128;
    const int nb = blockIdx.y * 128;

    long gA[4], gB[4];
    #pragma unroll
    for (int i = 0; i < 4; i++) {
        const int R = i * 32 + (t >> 3);
        const int l = (t & 7) ^ (R & 7);
        gA[i] = (long)(mb + R) * 1024 + l * 8;
        gB[i] = (long)(nb + R) * 1024 + l * 8;
    }
    short* lA = As + t * 8;
    short* lB = Bs + t * 8;

    f32x4 acc[4][4] = {};

    for (int k0 = 0; k0 < 1024; k0 += 64) {
        __syncthreads();
        #pragma unroll
        for (int i = 0; i < 4; i++) GLOAD_LDS(X + gA[i] + k0, lA + i * 2048);
        #pragma unroll
        for (int i = 0; i < 4; i++) GLOAD_LDS(W + gB[i] + k0, lB + i * 2048);
        __syncthreads();

        #pragma unroll
        for (int kh = 0; kh < 2; kh++) {
            short8 a[4], b[4];
            #pragma unroll
            for (int mt = 0; mt < 4; mt++) {
                const int r = wm * 64 + mt * 16 + l15;
                const int phys = (g + kh * 4) ^ (r & 7);
                a[mt] = *(const short8*)(As + r * 64 + phys * 8);
            }
            #pragma unroll
            for (int nt = 0; nt < 4; nt++) {
                const int r = wn * 64 + nt * 16 + l15;
                const int phys = (g + kh * 4) ^ (r & 7);
                b[nt] = *(const short8*)(Bs + r * 64 + phys * 8);
            }
            #pragma unroll
            for (int mt = 0; mt < 4; mt++)
                #pragma unroll
                for (int nt = 0; nt < 4; nt++)
                    acc[mt][nt] = __builtin_amdgcn_mfma_f32_16x16x32_bf16(a[mt], b[nt], acc[mt][nt], 0, 0, 0);
        }
    }

    const int rg = g * 4;
    #pragma unroll
    for (int nt = 0; nt < 4; nt++) {
        const int col = nb + wn * 64 + nt * 16 + l15;
        const float bv_ = bf2f(bias[col]);
        const int h = col >> 6, d = col & 63;
        #pragma unroll
        for (int mt = 0; mt < 4; mt++) {
            #pragma unroll
            for (int r = 0; r < 4; r++) {
                const int row = mb + wm * 64 + mt * 16 + rg + r;  // b*S + s
                const int bI = row >> 11, s = row & 2047;
                Out[(((long)(bI * NH + h) * S_LEN) + s) * DK + d] = f2bf(acc[mt][nt][r] + bv_);
            }
        }
    }
}

// ---------------- Out-proj: 128x64 tiles, BK=32 (R9 form), 512 blocks, f32 out ------
__global__ __launch_bounds__(256) void o_gemm(float* __restrict__ Out)
{
    __shared__ __attribute__((aligned(16))) short As[128 * 32];
    __shared__ __attribute__((aligned(16))) short Bs[64 * 32];

    const short* __restrict__ A = g_AO;
    const short* __restrict__ W = g_W + 3L * W_ELEMS;

    const int t = threadIdx.x;
    const int lane = t & 63;
    const int wid  = t >> 6;
    const int wm = wid & 1, wn = wid >> 1;     // wave tile 64x32
    const int l15 = lane & 15;
    const int q8  = (lane >> 4) * 8;
    const int mb = blockIdx.x * 128;
    const int nb = blockIdx.y * 64;

    const long ga0 = (long)(mb + (t >> 2)) * 1024 + (t & 3) * 8;
    const long ga1 = (long)(mb + 64 + (t >> 2)) * 1024 + (t & 3) * 8;
    const long gb0 = (long)(nb + (t >> 2)) * 1024 + (t & 3) * 8;
    short* lA0 = As + t * 8;
    short* lA1 = As + 2048 + t * 8;
    short* lB0 = Bs + t * 8;

    f32x4 acc[4][2] = {};

    for (int k0 = 0; k0 < 1024; k0 += 32) {
        __syncthreads();
        GLOAD_LDS(A + ga0 + k0, lA0);
        GLOAD_LDS(A + ga1 + k0, lA1);
        GLOAD_LDS(W + gb0 + k0, lB0);
        __syncthreads();

        short8 a[4], b[2];
        #pragma unroll
        for (int mt = 0; mt < 4; mt++) a[mt] = *(const short8*)(As + (wm * 64 + mt * 16 + l15) * 32 + q8);
        #pragma unroll
        for (int nt = 0; nt < 2; nt++) b[nt] = *(const short8*)(Bs + (wn * 32 + nt * 16 + l15) * 32 + q8);
        #pragma unroll
        for (int mt = 0; mt < 4; mt++)
            #pragma unroll
            for (int nt = 0; nt < 2; nt++)
                acc[mt][nt] = __builtin_amdgcn_mfma_f32_16x16x32_bf16(a[mt], b[nt], acc[mt][nt], 0, 0, 0);
    }

    const int rg = (lane >> 4) * 4;
    #pragma unroll
    for (int nt = 0; nt < 2; nt++) {
        const int col = nb + wn * 32 + nt * 16 + l15;
        const float bv_ = bf2f(g_b[3 * 1024 + col]);
        #pragma unroll
        for (int mt = 0; mt < 4; mt++) {
            #pragma unroll
            for (int r = 0; r < 4; r++) {
                const int row = mb + wm * 64 + mt * 16 + rg + r;
                Out[(long)row * 1024 + col] = acc[mt][nt][r] + bv_;
            }
        }
    }
}

// ------- Banded attention: single-pass softmax, whole-band prestage, XCD swizzle ----
// bid = qt*32 + head => bid%8 == head%8: all q-tiles of a head land on one XCD (if %8 RR).
#define VT_PAD 328   // row stride in shorts: 656 B = 164 dw == 4 (mod 32) bank skew

__global__ __launch_bounds__(256) void attn_kernel()
{
    __shared__ __attribute__((aligned(16))) short Vt[64][VT_PAD];   // [dim][key-kb0]
    __shared__ __attribute__((aligned(16))) short Pl[4][16][72];    // per-wave P [row][key]

    const int bid  = blockIdx.x;
    const int head = bid & 31;          // b*16+h
    const int qt   = bid >> 5;
    const int h = head & 15, b = head >> 4;
    const int qbase = qt * 64;

    const int lane = threadIdx.x & 63;
    const int w    = threadIdx.x >> 6;
    const int l15  = lane & 15;
    const int qg   = lane >> 4;
    const int q8   = qg * 8;

    const long hoff = (long)(b * NH + h) * S_LEN * DK;
    const short* __restrict__ Qh = g_Q + hoff;
    const short* __restrict__ Kh = g_K + hoff;
    const short* __restrict__ Vh = g_V + hoff;

    const int lo  = qbase - (BANDW - 1);
    const int kc0 = (lo < 0 ? 0 : lo) >> 6;
    int hi = qbase + 64 + (BANDW - 1);
    if (hi > S_LEN) hi = S_LEN;
    const int kc1 = (hi + 63) >> 6;
    const int kb0 = kc0 * 64;
    const int nkc = kc1 - kc0;                 // 3..5
    const int n_keys = nkc * 64;               // <= 320

    const short* qp = Qh + (long)(qbase + w * 16 + l15) * DK + q8;
    const short8 aq0 = *(const short8*)(qp);
    const short8 aq1 = *(const short8*)(qp + 32);

    // ---- stage whole-band V^T, two keys per thread, paired 4B writes ----
    const int npairs = n_keys >> 1;
    for (int u = threadIdx.x; u < npairs; u += 256) {
        const short* vp0 = Vh + (long)(kb0 + 2 * u) * DK;
        #pragma unroll
        for (int tq = 0; tq < 8; tq++) {
            const short8 v0 = *(const short8*)(vp0 + tq * 8);
            const short8 v1 = *(const short8*)(vp0 + DK + tq * 8);
            #pragma unroll
            for (int e = 0; e < 8; e++) {
                const int pk = (int)(unsigned short)v0[e] | ((int)(unsigned short)v1[e] << 16);
                *(int*)&Vt[tq * 8 + e][2 * u] = pk;
            }
        }
    }
    __syncthreads();   // only block barrier

    // ---- pass 1: all chunk scores into registers (static 5, live-guarded) ----
    f32x4 sc[5][4];
    float mx[4] = {-1e30f, -1e30f, -1e30f, -1e30f};
    #pragma unroll
    for (int c = 0; c < 5; c++) {
        const bool live = (c < nkc);
        const int kb = kb0 + (live ? c : 0) * 64;
        #pragma unroll
        for (int nt = 0; nt < 4; nt++) {
            const short* kp = Kh + (long)(kb + nt * 16 + l15) * DK + q8;
            const short8 bk0 = *(const short8*)(kp);
            const short8 bk1 = *(const short8*)(kp + 32);
            f32x4 z = {};
            z = __builtin_amdgcn_mfma_f32_16x16x32_bf16(aq0, bk0, z, 0, 0, 0);
            z = __builtin_amdgcn_mfma_f32_16x16x32_bf16(aq1, bk1, z, 0, 0, 0);
            const int kg = kb + nt * 16 + l15;
            #pragma unroll
            for (int r = 0; r < 4; r++) {
                const int qI = qbase + w * 16 + qg * 4 + r;
                int dlt = qI - kg; if (dlt < 0) dlt = -dlt;
                const float v = (live && dlt < BANDW) ? z[r] * 0.125f : -1e30f;
                sc[c][nt][r] = v;
                mx[r] = fmaxf(mx[r], v);
            }
        }
    }
    #pragma unroll
    for (int mk = 1; mk < 16; mk <<= 1)
        #pragma unroll
        for (int r = 0; r < 4; r++) mx[r] = fmaxf(mx[r], __shfl_xor(mx[r], mk, 64));

    // ---- pass 2: exp + row-sum ----
    float lsum[4] = {0.f, 0.f, 0.f, 0.f};
    #pragma unroll
    for (int c = 0; c < 5; c++)
        #pragma unroll
        for (int nt = 0; nt < 4; nt++)
            #pragma unroll
            for (int r = 0; r < 4; r++) {
                const float p = (sc[c][nt][r] > -0.5e30f)
                    ? __builtin_exp2f((sc[c][nt][r] - mx[r]) * 1.44269504f) : 0.f;
                sc[c][nt][r] = p;
                lsum[r] += p;
            }
    #pragma unroll
    for (int mk = 1; mk < 16; mk <<= 1)
        #pragma unroll
        for (int r = 0; r < 4; r++) lsum[r] += __shfl_xor(lsum[r], mk, 64);

    // ---- pass 3: O = P V ----
    f32x4 o[4] = {};
    #pragma unroll
    for (int c = 0; c < 5; c++) {
        if (c >= nkc) break;
        const int kloc = c * 64;
        #pragma unroll
        for (int nt = 0; nt < 4; nt++)
            #pragma unroll
            for (int r = 0; r < 4; r++)
                Pl[w][qg * 4 + r][nt * 16 + l15] = f2bf(sc[c][nt][r]);
        asm volatile("s_waitcnt lgkmcnt(0)" ::: "memory");
        const short8 ap0 = *(const short8*)(&Pl[w][l15][q8]);
        const short8 ap1 = *(const short8*)(&Pl[w][l15][32 + q8]);

        #pragma unroll
        for (int nt2 = 0; nt2 < 4; nt2++) {
            const short* vrow = &Vt[nt2 * 16 + l15][kloc];
            const short8 bv0 = *(const short8*)(vrow + q8);
            const short8 bv1 = *(const short8*)(vrow + 32 + q8);
            o[nt2] = __builtin_amdgcn_mfma_f32_16x16x32_bf16(ap0, bv0, o[nt2], 0, 0, 0);
            o[nt2] = __builtin_amdgcn_mfma_f32_16x16x32_bf16(ap1, bv1, o[nt2], 0, 0, 0);
        }
    }

    #pragma unroll
    for (int nt2 = 0; nt2 < 4; nt2++)
        #pragma unroll
        for (int r = 0; r < 4; r++) {
            const int qI = qbase + w * 16 + qg * 4 + r;
            const int d = nt2 * 16 + l15;
            g_AO[((long)b * S_LEN + qI) * 1024 + h * DK + d] = f2bf(o[nt2][r] / lsum[r]);
        }
}

extern "C" void kernel_launch(void* const* d_in, const int* in_sizes, int n_in,
                              void* d_out, int out_size, void* d_ws, size_t ws_size,
                              hipStream_t stream) {
    float* out = (float*)d_out;

    convert_all<<<(TOTC + 255) / 256, 256, 0, stream>>>(
        d_in[0], d_in[1], d_in[2], d_in[3], d_in[4], d_in[5], d_in[6], d_in[7], d_in[8]);
    qkv_gemm<<<dim3(32, 8, 3), 256, 0, stream>>>();
    attn_kernel<<<dim3(2 * NH * (S_LEN / 64)), 256, 0, stream>>>();
    o_gemm<<<dim3(32, 16), 256, 0, stream>>>(out);
}

// Round 12
// 183.766 us; speedup vs baseline: 1.0051x; 1.0051x over previous
//
#include <hip/hip_runtime.h>
#include <hip/hip_bf16.h>

// B=2, S=2048, D=1024, H=16, DK=64, BAND=100. Inputs f32 (auto-detect; bf16 fallback).
// Output f32. 4 dispatches: convert_all (ballot detect) -> qkv_gemm (BK=64 swizzled)
// -> attn (128 q/block, shared K-frags, online softmax, XCD swizzle) -> o_gemm (BK=32).

typedef __attribute__((ext_vector_type(8))) short short8;
typedef __attribute__((ext_vector_type(4))) float f32x4;

#define S_LEN 2048
#define NH 16
#define DK 64
#define BANDW 100

#define X_ELEMS   (2 * S_LEN * 1024)
#define W_ELEMS   (1024 * 1024)
#define QKV_ELEMS (2 * NH * S_LEN * DK)
#define AO_ELEMS  (2 * S_LEN * 1024)

__device__ __attribute__((aligned(256))) short g_X[X_ELEMS];
__device__ __attribute__((aligned(256))) short g_W[4 * W_ELEMS];   // Wq|Wk|Wv|Wo
__device__ __attribute__((aligned(256))) short g_b[4 * 1024];      // bq|bk|bv|bo
__device__ __attribute__((aligned(256))) short g_Q[QKV_ELEMS];
__device__ __attribute__((aligned(256))) short g_K[QKV_ELEMS];
__device__ __attribute__((aligned(256))) short g_V[QKV_ELEMS];     // row-major [B,H,S,DK]
__device__ __attribute__((aligned(256))) short g_AO[AO_ELEMS];

__device__ __forceinline__ float bf2f(short u) {
    unsigned x = ((unsigned)(unsigned short)u) << 16;
    return __builtin_bit_cast(float, x);
}
__device__ __forceinline__ short f2bf(float f) {
    unsigned x = __builtin_bit_cast(unsigned, f);
    unsigned r = (x + 0x7fffu + ((x >> 16) & 1u)) >> 16;
    return (short)r;
}

#define GLOAD_LDS(gp, lp) \
    __builtin_amdgcn_global_load_lds( \
        (const __attribute__((address_space(1))) void*)(gp), \
        (__attribute__((address_space(3))) void*)(lp), 16, 0, 0)

// ---------------- Fused detect + convert (1 dispatch, all 9 tensors) ----------------
#define XC   (X_ELEMS / 8)
#define WC   (W_ELEMS / 8)
#define BC   (1024 / 8)
#define TOTC (XC + 4 * WC + 4 * BC)

__global__ __launch_bounds__(256) void convert_all(
    const void* __restrict__ x,
    const void* __restrict__ w0, const void* __restrict__ b0,
    const void* __restrict__ w1, const void* __restrict__ b1,
    const void* __restrict__ w2, const void* __restrict__ b2,
    const void* __restrict__ w3, const void* __restrict__ b3)
{
    int local = 0;
    {
        const unsigned* xw = (const unsigned*)x;
        #pragma unroll
        for (int i = 0; i < 4; i++) {
            unsigned wv = xw[(threadIdx.x & 63) * 4 + i];
            unsigned e = (wv >> 7) & 0xFF;
            if (e >= 100 && e <= 140) local++;
        }
    }
    const int is_bf16 = (__popcll(__ballot(local == 4)) > 32);

    long i = (long)blockIdx.x * 256 + threadIdx.x;
    if (i >= TOTC) return;

    const void* src; short* dst; long off;
    if (i < XC)                { src = x;  dst = g_X;              off = i; }
    else if ((i -= XC) < WC)   { src = w0; dst = g_W + 0L*W_ELEMS; off = i; }
    else if ((i -= WC) < WC)   { src = w1; dst = g_W + 1L*W_ELEMS; off = i; }
    else if ((i -= WC) < WC)   { src = w2; dst = g_W + 2L*W_ELEMS; off = i; }
    else if ((i -= WC) < WC)   { src = w3; dst = g_W + 3L*W_ELEMS; off = i; }
    else if ((i -= WC) < BC)   { src = b0; dst = g_b + 0*1024;     off = i; }
    else if ((i -= BC) < BC)   { src = b1; dst = g_b + 1*1024;     off = i; }
    else if ((i -= BC) < BC)   { src = b2; dst = g_b + 2*1024;     off = i; }
    else                       { src = b3; dst = g_b + 3*1024;     off = i - BC; }

    if (is_bf16) {
        ((short8*)dst)[off] = ((const short8*)src)[off];
    } else {
        const float* s = (const float*)src + off * 8;
        short8 o;
        #pragma unroll
        for (int e = 0; e < 8; e++) o[e] = f2bf(s[e]);
        ((short8*)dst)[off] = o;
    }
}

// ------------- QKV GEMM: 128x128 tile, BK=64, XOR-swizzled LDS (0 conflicts) --------
__global__ __launch_bounds__(256) void qkv_gemm()
{
    __shared__ __attribute__((aligned(16))) short As[128 * 64];
    __shared__ __attribute__((aligned(16))) short Bs[128 * 64];

    const int z = blockIdx.z;
    const short* __restrict__ X = g_X;
    const short* __restrict__ W = g_W + (long)z * W_ELEMS;
    const short* __restrict__ bias = g_b + z * 1024;
    short* __restrict__ Out = (z == 0) ? g_Q : ((z == 1) ? g_K : g_V);

    const int t = threadIdx.x;
    const int lane = t & 63;
    const int wid  = t >> 6;
    const int wm = wid & 1, wn = wid >> 1;
    const int l15 = lane & 15;
    const int g   = lane >> 4;
    const int mb = blockIdx.x * 128;
    const int nb = blockIdx.y * 128;

    long gA[4], gB[4];
    #pragma unroll
    for (int i = 0; i < 4; i++) {
        const int R = i * 32 + (t >> 3);
        const int l = (t & 7) ^ (R & 7);
        gA[i] = (long)(mb + R) * 1024 + l * 8;
        gB[i] = (long)(nb + R) * 1024 + l * 8;
    }
    short* lA = As + t * 8;
    short* lB = Bs + t * 8;

    f32x4 acc[4][4] = {};

    for (int k0 = 0; k0 < 1024; k0 += 64) {
        __syncthreads();
        #pragma unroll
        for (int i = 0; i < 4; i++) GLOAD_LDS(X + gA[i] + k0, lA + i * 2048);
        #pragma unroll
        for (int i = 0; i < 4; i++) GLOAD_LDS(W + gB[i] + k0, lB + i * 2048);
        __syncthreads();

        #pragma unroll
        for (int kh = 0; kh < 2; kh++) {
            short8 a[4], b[4];
            #pragma unroll
            for (int mt = 0; mt < 4; mt++) {
                const int r = wm * 64 + mt * 16 + l15;
                const int phys = (g + kh * 4) ^ (r & 7);
                a[mt] = *(const short8*)(As + r * 64 + phys * 8);
            }
            #pragma unroll
            for (int nt = 0; nt < 4; nt++) {
                const int r = wn * 64 + nt * 16 + l15;
                const int phys = (g + kh * 4) ^ (r & 7);
                b[nt] = *(const short8*)(Bs + r * 64 + phys * 8);
            }
            #pragma unroll
            for (int mt = 0; mt < 4; mt++)
                #pragma unroll
                for (int nt = 0; nt < 4; nt++)
                    acc[mt][nt] = __builtin_amdgcn_mfma_f32_16x16x32_bf16(a[mt], b[nt], acc[mt][nt], 0, 0, 0);
        }
    }

    const int rg = g * 4;
    #pragma unroll
    for (int nt = 0; nt < 4; nt++) {
        const int col = nb + wn * 64 + nt * 16 + l15;
        const float bv_ = bf2f(bias[col]);
        const int h = col >> 6, d = col & 63;
        #pragma unroll
        for (int mt = 0; mt < 4; mt++) {
            #pragma unroll
            for (int r = 0; r < 4; r++) {
                const int row = mb + wm * 64 + mt * 16 + rg + r;  // b*S + s
                const int bI = row >> 11, s = row & 2047;
                Out[(((long)(bI * NH + h) * S_LEN) + s) * DK + d] = f2bf(acc[mt][nt][r] + bv_);
            }
        }
    }
}

// ---------------- Out-proj: 128x64 tiles, BK=32, 512 blocks, f32 out ----------------
__global__ __launch_bounds__(256) void o_gemm(float* __restrict__ Out)
{
    __shared__ __attribute__((aligned(16))) short As[128 * 32];
    __shared__ __attribute__((aligned(16))) short Bs[64 * 32];

    const short* __restrict__ A = g_AO;
    const short* __restrict__ W = g_W + 3L * W_ELEMS;

    const int t = threadIdx.x;
    const int lane = t & 63;
    const int wid  = t >> 6;
    const int wm = wid & 1, wn = wid >> 1;
    const int l15 = lane & 15;
    const int q8  = (lane >> 4) * 8;
    const int mb = blockIdx.x * 128;
    const int nb = blockIdx.y * 64;

    const long ga0 = (long)(mb + (t >> 2)) * 1024 + (t & 3) * 8;
    const long ga1 = (long)(mb + 64 + (t >> 2)) * 1024 + (t & 3) * 8;
    const long gb0 = (long)(nb + (t >> 2)) * 1024 + (t & 3) * 8;
    short* lA0 = As + t * 8;
    short* lA1 = As + 2048 + t * 8;
    short* lB0 = Bs + t * 8;

    f32x4 acc[4][2] = {};

    for (int k0 = 0; k0 < 1024; k0 += 32) {
        __syncthreads();
        GLOAD_LDS(A + ga0 + k0, lA0);
        GLOAD_LDS(A + ga1 + k0, lA1);
        GLOAD_LDS(W + gb0 + k0, lB0);
        __syncthreads();

        short8 a[4], b[2];
        #pragma unroll
        for (int mt = 0; mt < 4; mt++) a[mt] = *(const short8*)(As + (wm * 64 + mt * 16 + l15) * 32 + q8);
        #pragma unroll
        for (int nt = 0; nt < 2; nt++) b[nt] = *(const short8*)(Bs + (wn * 32 + nt * 16 + l15) * 32 + q8);
        #pragma unroll
        for (int mt = 0; mt < 4; mt++)
            #pragma unroll
            for (int nt = 0; nt < 2; nt++)
                acc[mt][nt] = __builtin_amdgcn_mfma_f32_16x16x32_bf16(a[mt], b[nt], acc[mt][nt], 0, 0, 0);
    }

    const int rg = (lane >> 4) * 4;
    #pragma unroll
    for (int nt = 0; nt < 2; nt++) {
        const int col = nb + wn * 32 + nt * 16 + l15;
        const float bv_ = bf2f(g_b[3 * 1024 + col]);
        #pragma unroll
        for (int mt = 0; mt < 4; mt++) {
            #pragma unroll
            for (int r = 0; r < 4; r++) {
                const int row = mb + wm * 64 + mt * 16 + rg + r;
                Out[(long)row * 1024 + col] = acc[mt][nt][r] + bv_;
            }
        }
    }
}

// ------- Banded attention: 128 queries/block, shared K-frags, online softmax --------
// bid = qt*32 + head  =>  head%8 fixed per XCD (4 heads/XCD, K+V ~2MB < 4MB L2).
// Each wave owns two 16-query groups (g2=0: qbase+w*16, g2=1: qbase+64+w*16).
// Band of 128 queries spans <= 6 chunks of 64 keys; V^T prestaged once (1 barrier).
#define VT_PAD 392   // 392 shorts = 196 dw; 196%32=4 -> 4-bank row skew (2-way, free)

__global__ __launch_bounds__(256) void attn_kernel()
{
    __shared__ __attribute__((aligned(16))) short Vt[64][VT_PAD];   // [dim][key-kb0]
    __shared__ __attribute__((aligned(16))) short Pl[4][16][72];    // per-wave P [row][key]

    const int bid  = blockIdx.x;
    const int head = bid & 31;          // b*16+h
    const int qt   = bid >> 5;          // 0..15
    const int h = head & 15, b = head >> 4;
    const int qbase = qt * 128;

    const int lane = threadIdx.x & 63;
    const int w    = threadIdx.x >> 6;
    const int l15  = lane & 15;
    const int qg   = lane >> 4;
    const int q8   = qg * 8;

    const long hoff = (long)(b * NH + h) * S_LEN * DK;
    const short* __restrict__ Qh = g_Q + hoff;
    const short* __restrict__ Kh = g_K + hoff;
    const short* __restrict__ Vh = g_V + hoff;

    const int lo  = qbase - (BANDW - 1);
    const int kc0 = (lo < 0 ? 0 : lo) >> 6;
    int hi = qbase + 128 + (BANDW - 1);
    if (hi > S_LEN) hi = S_LEN;
    const int kc1 = (hi + 63) >> 6;
    const int kb0 = kc0 * 64;
    const int n_keys = (kc1 - kc0) * 64;        // <= 384

    // Q fragments for both groups
    short8 aq0[2], aq1[2];
    #pragma unroll
    for (int g2 = 0; g2 < 2; g2++) {
        const short* qp = Qh + (long)(qbase + g2 * 64 + w * 16 + l15) * DK + q8;
        aq0[g2] = *(const short8*)(qp);
        aq1[g2] = *(const short8*)(qp + 32);
    }

    // ---- stage whole-band V^T once (paired 4B writes), single barrier ----
    const int npairs = n_keys >> 1;
    for (int u = threadIdx.x; u < npairs; u += 256) {
        const short* vp0 = Vh + (long)(kb0 + 2 * u) * DK;
        #pragma unroll
        for (int tq = 0; tq < 8; tq++) {
            const short8 v0 = *(const short8*)(vp0 + tq * 8);
            const short8 v1 = *(const short8*)(vp0 + DK + tq * 8);
            #pragma unroll
            for (int e = 0; e < 8; e++) {
                const int pk = (int)(unsigned short)v0[e] | ((int)(unsigned short)v1[e] << 16);
                *(int*)&Vt[tq * 8 + e][2 * u] = pk;
            }
        }
    }
    __syncthreads();   // only block barrier

    f32x4 o[2][4] = {};
    float m_r[2][4], l_r[2][4];
    #pragma unroll
    for (int g2 = 0; g2 < 2; g2++)
        #pragma unroll
        for (int r = 0; r < 4; r++) { m_r[g2][r] = -1e30f; l_r[g2][r] = 0.f; }

    for (int kc = kc0; kc < kc1; kc++) {
        const int kb = kc * 64;
        const int kloc = kb - kb0;

        // K fragments for this chunk — loaded ONCE, shared by both groups
        short8 bk0[4], bk1[4];
        #pragma unroll
        for (int nt = 0; nt < 4; nt++) {
            const short* kp = Kh + (long)(kb + nt * 16 + l15) * DK + q8;
            bk0[nt] = *(const short8*)(kp);
            bk1[nt] = *(const short8*)(kp + 32);
        }

        #pragma unroll
        for (int g2 = 0; g2 < 2; g2++) {
            const int gqb = qbase + g2 * 64;
            // chunk outside this group's band? (keys allowed: (gqb-100, gqb+162])
            if (kb + 163 <= gqb || kb >= gqb + 163) continue;

            f32x4 sc[4];
            #pragma unroll
            for (int nt = 0; nt < 4; nt++) {
                f32x4 z = {};
                z = __builtin_amdgcn_mfma_f32_16x16x32_bf16(aq0[g2], bk0[nt], z, 0, 0, 0);
                z = __builtin_amdgcn_mfma_f32_16x16x32_bf16(aq1[g2], bk1[nt], z, 0, 0, 0);
                sc[nt] = z;
            }

            float pv[4][4];
            float mx[4] = {-1e30f, -1e30f, -1e30f, -1e30f};
            #pragma unroll
            for (int nt = 0; nt < 4; nt++) {
                const int kg = kb + nt * 16 + l15;
                #pragma unroll
                for (int r = 0; r < 4; r++) {
                    const int qI = gqb + w * 16 + qg * 4 + r;
                    int dlt = qI - kg; if (dlt < 0) dlt = -dlt;
                    const float v = (dlt < BANDW) ? sc[nt][r] * 0.125f : -1e30f;
                    pv[nt][r] = v;
                    mx[r] = fmaxf(mx[r], v);
                }
            }
            #pragma unroll
            for (int mk = 1; mk < 16; mk <<= 1)
                #pragma unroll
                for (int r = 0; r < 4; r++) mx[r] = fmaxf(mx[r], __shfl_xor(mx[r], mk, 64));

            float alpha[4], lnew[4];
            #pragma unroll
            for (int r = 0; r < 4; r++) {
                const float mn = fmaxf(m_r[g2][r], mx[r]);
                alpha[r] = __builtin_exp2f((m_r[g2][r] - mn) * 1.44269504f);
                m_r[g2][r] = mn;
                lnew[r] = 0.f;
            }
            #pragma unroll
            for (int nt = 0; nt < 4; nt++)
                #pragma unroll
                for (int r = 0; r < 4; r++) {
                    const float p = (pv[nt][r] > -0.5e30f)
                        ? __builtin_exp2f((pv[nt][r] - m_r[g2][r]) * 1.44269504f) : 0.f;
                    pv[nt][r] = p;
                    lnew[r] += p;
                }
            #pragma unroll
            for (int mk = 1; mk < 16; mk <<= 1)
                #pragma unroll
                for (int r = 0; r < 4; r++) lnew[r] += __shfl_xor(lnew[r], mk, 64);
            #pragma unroll
            for (int r = 0; r < 4; r++) l_r[g2][r] = l_r[g2][r] * alpha[r] + lnew[r];
            #pragma unroll
            for (int nt2 = 0; nt2 < 4; nt2++)
                #pragma unroll
                for (int r = 0; r < 4; r++) o[g2][nt2][r] *= alpha[r];

            // P (C layout) -> per-wave LDS -> A layout (same-wave DS ordering, lgkm only)
            #pragma unroll
            for (int nt = 0; nt < 4; nt++)
                #pragma unroll
                for (int r = 0; r < 4; r++)
                    Pl[w][qg * 4 + r][nt * 16 + l15] = f2bf(pv[nt][r]);
            asm volatile("s_waitcnt lgkmcnt(0)" ::: "memory");
            const short8 ap0 = *(const short8*)(&Pl[w][l15][q8]);
            const short8 ap1 = *(const short8*)(&Pl[w][l15][32 + q8]);

            #pragma unroll
            for (int nt2 = 0; nt2 < 4; nt2++) {
                const short* vrow = &Vt[nt2 * 16 + l15][kloc];
                const short8 bv0 = *(const short8*)(vrow + q8);
                const short8 bv1 = *(const short8*)(vrow + 32 + q8);
                o[g2][nt2] = __builtin_amdgcn_mfma_f32_16x16x32_bf16(ap0, bv0, o[g2][nt2], 0, 0, 0);
                o[g2][nt2] = __builtin_amdgcn_mfma_f32_16x16x32_bf16(ap1, bv1, o[g2][nt2], 0, 0, 0);
            }
        }
    }

    #pragma unroll
    for (int g2 = 0; g2 < 2; g2++)
        #pragma unroll
        for (int nt2 = 0; nt2 < 4; nt2++)
            #pragma unroll
            for (int r = 0; r < 4; r++) {
                const int qI = qbase + g2 * 64 + w * 16 + qg * 4 + r;
                const int d = nt2 * 16 + l15;
                g_AO[((long)b * S_LEN + qI) * 1024 + h * DK + d] = f2bf(o[g2][nt2][r] / l_r[g2][r]);
            }
}

extern "C" void kernel_launch(void* const* d_in, const int* in_sizes, int n_in,
                              void* d_out, int out_size, void* d_ws, size_t ws_size,
                              hipStream_t stream) {
    float* out = (float*)d_out;

    convert_all<<<(TOTC + 255) / 256, 256, 0, stream>>>(
        d_in[0], d_in[1], d_in[2], d_in[3], d_in[4], d_in[5], d_in[6], d_in[7], d_in[8]);
    qkv_gemm<<<dim3(32, 8, 3), 256, 0, stream>>>();
    attn_kernel<<<dim3(2 * NH * (S_LEN / 128)), 256, 0, stream>>>();
    o_gemm<<<dim3(32, 16), 256, 0, stream>>>(out);
}

// Round 13
// 175.657 us; speedup vs baseline: 1.0515x; 1.0462x over previous
//
#include <hip/hip_runtime.h>
#include <hip/hip_bf16.h>

// B=2, S=2048, D=1024, H=16, DK=64, BAND=100. Inputs f32 (auto-detect; bf16 fallback).
// Output f32. R9 base config + attn-only changes: K-prefetch pipeline, XCD swizzle,
// scale folded into Q projection, diagonal-chunk fast path.

typedef __attribute__((ext_vector_type(8))) short short8;
typedef __attribute__((ext_vector_type(4))) float f32x4;

#define S_LEN 2048
#define NH 16
#define DK 64
#define BANDW 100

#define X_ELEMS   (2 * S_LEN * 1024)
#define W_ELEMS   (1024 * 1024)
#define QKV_ELEMS (2 * NH * S_LEN * DK)
#define AO_ELEMS  (2 * S_LEN * 1024)

__device__ __attribute__((aligned(256))) short g_X[X_ELEMS];
__device__ __attribute__((aligned(256))) short g_W[4 * W_ELEMS];   // Wq|Wk|Wv|Wo
__device__ __attribute__((aligned(256))) short g_b[4 * 1024];      // bq|bk|bv|bo
__device__ __attribute__((aligned(256))) short g_Q[QKV_ELEMS];     // pre-scaled by 1/8
__device__ __attribute__((aligned(256))) short g_K[QKV_ELEMS];
__device__ __attribute__((aligned(256))) short g_V[QKV_ELEMS];     // row-major [B,H,S,DK]
__device__ __attribute__((aligned(256))) short g_AO[AO_ELEMS];

__device__ __forceinline__ float bf2f(short u) {
    unsigned x = ((unsigned)(unsigned short)u) << 16;
    return __builtin_bit_cast(float, x);
}
__device__ __forceinline__ short f2bf(float f) {
    unsigned x = __builtin_bit_cast(unsigned, f);
    unsigned r = (x + 0x7fffu + ((x >> 16) & 1u)) >> 16;
    return (short)r;
}

#define GLOAD_LDS(gp, lp) \
    __builtin_amdgcn_global_load_lds( \
        (const __attribute__((address_space(1))) void*)(gp), \
        (__attribute__((address_space(3))) void*)(lp), 16, 0, 0)

// ---------------- Fused detect + convert (R9 form) ----------------
#define XC   (X_ELEMS / 8)
#define WC   (W_ELEMS / 8)
#define BC   (1024 / 8)
#define TOTC (XC + 4 * WC + 4 * BC)

__global__ __launch_bounds__(256) void convert_all(
    const void* __restrict__ x,
    const void* __restrict__ w0, const void* __restrict__ b0,
    const void* __restrict__ w1, const void* __restrict__ b1,
    const void* __restrict__ w2, const void* __restrict__ b2,
    const void* __restrict__ w3, const void* __restrict__ b3)
{
    __shared__ int cnt[256];
    {
        const unsigned* xw = (const unsigned*)x;
        int local = 0;
        #pragma unroll
        for (int i = 0; i < 4; i++) {
            unsigned wv = xw[threadIdx.x * 4 + i];
            unsigned e = (wv >> 7) & 0xFF;
            if (e >= 100 && e <= 140) local++;
        }
        cnt[threadIdx.x] = local;
    }
    __syncthreads();
    for (int s = 128; s > 0; s >>= 1) {
        if (threadIdx.x < s) cnt[threadIdx.x] += cnt[threadIdx.x + s];
        __syncthreads();
    }
    const int is_bf16 = (cnt[0] > 512);

    long i = (long)blockIdx.x * 256 + threadIdx.x;
    if (i >= TOTC) return;

    const void* src; short* dst; long off;
    if (i < XC)                { src = x;  dst = g_X;              off = i; }
    else if ((i -= XC) < WC)   { src = w0; dst = g_W + 0L*W_ELEMS; off = i; }
    else if ((i -= WC) < WC)   { src = w1; dst = g_W + 1L*W_ELEMS; off = i; }
    else if ((i -= WC) < WC)   { src = w2; dst = g_W + 2L*W_ELEMS; off = i; }
    else if ((i -= WC) < WC)   { src = w3; dst = g_W + 3L*W_ELEMS; off = i; }
    else if ((i -= WC) < BC)   { src = b0; dst = g_b + 0*1024;     off = i; }
    else if ((i -= BC) < BC)   { src = b1; dst = g_b + 1*1024;     off = i; }
    else if ((i -= BC) < BC)   { src = b2; dst = g_b + 2*1024;     off = i; }
    else                       { src = b3; dst = g_b + 3*1024;     off = i - BC; }

    if (is_bf16) {
        ((short8*)dst)[off] = ((const short8*)src)[off];
    } else {
        const float* s = (const float*)src + off * 8;
        short8 o;
        #pragma unroll
        for (int e = 0; e < 8; e++) o[e] = f2bf(s[e]);
        ((short8*)dst)[off] = o;
    }
}

// ---------------- QKV GEMM (R9 form: 128x128, BK=32, LDS-staged) --------------------
// z==0 (Q) epilogue folds the 1/sqrt(dk)=0.125 attention scale.
__global__ __launch_bounds__(256) void qkv_gemm()
{
    __shared__ __attribute__((aligned(16))) short As[128 * 32];
    __shared__ __attribute__((aligned(16))) short Bs[128 * 32];

    const int z = blockIdx.z;
    const short* __restrict__ X = g_X;
    const short* __restrict__ W = g_W + (long)z * W_ELEMS;
    const short* __restrict__ bias = g_b + z * 1024;
    short* __restrict__ Out = (z == 0) ? g_Q : ((z == 1) ? g_K : g_V);
    const float scale = (z == 0) ? 0.125f : 1.0f;

    const int t = threadIdx.x;
    const int lane = t & 63;
    const int wid  = t >> 6;
    const int wm = wid & 1, wn = wid >> 1;
    const int l15 = lane & 15;
    const int q8  = (lane >> 4) * 8;
    const int mb = blockIdx.x * 128;
    const int nb = blockIdx.y * 128;

    const long ga0 = (long)(mb + (t >> 2)) * 1024 + (t & 3) * 8;
    const long ga1 = (long)(mb + 64 + (t >> 2)) * 1024 + (t & 3) * 8;
    const long gb0 = (long)(nb + (t >> 2)) * 1024 + (t & 3) * 8;
    const long gb1 = (long)(nb + 64 + (t >> 2)) * 1024 + (t & 3) * 8;
    short* lA0 = As + t * 8;
    short* lA1 = As + 2048 + t * 8;
    short* lB0 = Bs + t * 8;
    short* lB1 = Bs + 2048 + t * 8;

    f32x4 acc[4][4] = {};

    for (int k0 = 0; k0 < 1024; k0 += 32) {
        __syncthreads();
        GLOAD_LDS(X + ga0 + k0, lA0);
        GLOAD_LDS(X + ga1 + k0, lA1);
        GLOAD_LDS(W + gb0 + k0, lB0);
        GLOAD_LDS(W + gb1 + k0, lB1);
        __syncthreads();

        short8 a[4], b[4];
        #pragma unroll
        for (int mt = 0; mt < 4; mt++) a[mt] = *(const short8*)(As + (wm * 64 + mt * 16 + l15) * 32 + q8);
        #pragma unroll
        for (int nt = 0; nt < 4; nt++) b[nt] = *(const short8*)(Bs + (wn * 64 + nt * 16 + l15) * 32 + q8);
        #pragma unroll
        for (int mt = 0; mt < 4; mt++)
            #pragma unroll
            for (int nt = 0; nt < 4; nt++)
                acc[mt][nt] = __builtin_amdgcn_mfma_f32_16x16x32_bf16(a[mt], b[nt], acc[mt][nt], 0, 0, 0);
    }

    const int rg = (lane >> 4) * 4;
    #pragma unroll
    for (int nt = 0; nt < 4; nt++) {
        const int col = nb + wn * 64 + nt * 16 + l15;
        const float bv_ = bf2f(bias[col]);
        const int h = col >> 6, d = col & 63;
        #pragma unroll
        for (int mt = 0; mt < 4; mt++) {
            #pragma unroll
            for (int r = 0; r < 4; r++) {
                const int row = mb + wm * 64 + mt * 16 + rg + r;  // b*S + s
                const int bI = row >> 11, s = row & 2047;
                Out[(((long)(bI * NH + h) * S_LEN) + s) * DK + d] = f2bf((acc[mt][nt][r] + bv_) * scale);
            }
        }
    }
}

// ---------------- Out-proj (R9 form): 128x64 tiles, BK=32, 512 blocks ---------------
__global__ __launch_bounds__(256) void o_gemm(float* __restrict__ Out)
{
    __shared__ __attribute__((aligned(16))) short As[128 * 32];
    __shared__ __attribute__((aligned(16))) short Bs[64 * 32];

    const short* __restrict__ A = g_AO;
    const short* __restrict__ W = g_W + 3L * W_ELEMS;

    const int t = threadIdx.x;
    const int lane = t & 63;
    const int wid  = t >> 6;
    const int wm = wid & 1, wn = wid >> 1;
    const int l15 = lane & 15;
    const int q8  = (lane >> 4) * 8;
    const int mb = blockIdx.x * 128;
    const int nb = blockIdx.y * 64;

    const long ga0 = (long)(mb + (t >> 2)) * 1024 + (t & 3) * 8;
    const long ga1 = (long)(mb + 64 + (t >> 2)) * 1024 + (t & 3) * 8;
    const long gb0 = (long)(nb + (t >> 2)) * 1024 + (t & 3) * 8;
    short* lA0 = As + t * 8;
    short* lA1 = As + 2048 + t * 8;
    short* lB0 = Bs + t * 8;

    f32x4 acc[4][2] = {};

    for (int k0 = 0; k0 < 1024; k0 += 32) {
        __syncthreads();
        GLOAD_LDS(A + ga0 + k0, lA0);
        GLOAD_LDS(A + ga1 + k0, lA1);
        GLOAD_LDS(W + gb0 + k0, lB0);
        __syncthreads();

        short8 a[4], b[2];
        #pragma unroll
        for (int mt = 0; mt < 4; mt++) a[mt] = *(const short8*)(As + (wm * 64 + mt * 16 + l15) * 32 + q8);
        #pragma unroll
        for (int nt = 0; nt < 2; nt++) b[nt] = *(const short8*)(Bs + (wn * 32 + nt * 16 + l15) * 32 + q8);
        #pragma unroll
        for (int mt = 0; mt < 4; mt++)
            #pragma unroll
            for (int nt = 0; nt < 2; nt++)
                acc[mt][nt] = __builtin_amdgcn_mfma_f32_16x16x32_bf16(a[mt], b[nt], acc[mt][nt], 0, 0, 0);
    }

    const int rg = (lane >> 4) * 4;
    #pragma unroll
    for (int nt = 0; nt < 2; nt++) {
        const int col = nb + wn * 32 + nt * 16 + l15;
        const float bv_ = bf2f(g_b[3 * 1024 + col]);
        #pragma unroll
        for (int mt = 0; mt < 4; mt++) {
            #pragma unroll
            for (int r = 0; r < 4; r++) {
                const int row = mb + wm * 64 + mt * 16 + rg + r;
                Out[(long)row * 1024 + col] = acc[mt][nt][r] + bv_;
            }
        }
    }
}

// ------- Banded attention: 64 q/block, online softmax, K prefetch, XCD swizzle ------
// bid = qt*32 + head  =>  bid%8 == head%8: one head's q-tiles share an XCD L2.
#define VT_PAD 328   // 656 B = 164 dw; 164%32=4 -> 4-bank row skew (2-way, free)

__global__ __launch_bounds__(256) void attn_kernel()
{
    __shared__ __attribute__((aligned(16))) short Vt[64][VT_PAD];   // [dim][key-kb0]
    __shared__ __attribute__((aligned(16))) short Pl[4][16][72];    // per-wave P [row][key]

    const int bid  = blockIdx.x;
    const int head = bid & 31;          // b*16+h
    const int qt   = bid >> 5;          // 0..31
    const int h = head & 15, b = head >> 4;
    const int qbase = qt * 64;

    const int lane = threadIdx.x & 63;
    const int w    = threadIdx.x >> 6;
    const int l15  = lane & 15;
    const int qg   = lane >> 4;
    const int q8   = qg * 8;

    const long hoff = (long)(b * NH + h) * S_LEN * DK;
    const short* __restrict__ Qh = g_Q + hoff;
    const short* __restrict__ Kh = g_K + hoff;
    const short* __restrict__ Vh = g_V + hoff;

    const int lo  = qbase - (BANDW - 1);
    const int kc0 = (lo < 0 ? 0 : lo) >> 6;
    int hi = qbase + 64 + (BANDW - 1);
    if (hi > S_LEN) hi = S_LEN;
    const int kc1 = (hi + 63) >> 6;
    const int kb0 = kc0 * 64;
    const int n_keys = (kc1 - kc0) * 64;   // <= 320

    // Q fragments (already pre-scaled by 1/8 at projection)
    const short* qp = Qh + (long)(qbase + w * 16 + l15) * DK + q8;
    const short8 aq0 = *(const short8*)(qp);
    const short8 aq1 = *(const short8*)(qp + 32);

    // ---- stage whole-band V^T, two keys per thread, paired 4B writes ----
    const int npairs = n_keys >> 1;
    for (int u = threadIdx.x; u < npairs; u += 256) {
        const short* vp0 = Vh + (long)(kb0 + 2 * u) * DK;
        #pragma unroll
        for (int tq = 0; tq < 8; tq++) {
            const short8 v0 = *(const short8*)(vp0 + tq * 8);
            const short8 v1 = *(const short8*)(vp0 + DK + tq * 8);
            #pragma unroll
            for (int e = 0; e < 8; e++) {
                const int pk = (int)(unsigned short)v0[e] | ((int)(unsigned short)v1[e] << 16);
                *(int*)&Vt[tq * 8 + e][2 * u] = pk;
            }
        }
    }
    __syncthreads();   // only block barrier

    // ---- prefetch first chunk's K fragments ----
    short8 nk0[4], nk1[4];
    #pragma unroll
    for (int nt = 0; nt < 4; nt++) {
        const short* kp = Kh + (long)(kb0 + nt * 16 + l15) * DK + q8;
        nk0[nt] = *(const short8*)(kp);
        nk1[nt] = *(const short8*)(kp + 32);
    }

    f32x4 o[4] = {};
    float m_r[4], l_r[4];
    #pragma unroll
    for (int r = 0; r < 4; r++) { m_r[r] = -1e30f; l_r[r] = 0.f; }

    for (int kc = kc0; kc < kc1; kc++) {
        const int kb = kc * 64;
        const int kloc = kb - kb0;

        // consume prefetched K; immediately issue next chunk's loads
        short8 bk0[4], bk1[4];
        #pragma unroll
        for (int nt = 0; nt < 4; nt++) { bk0[nt] = nk0[nt]; bk1[nt] = nk1[nt]; }
        if (kc + 1 < kc1) {
            const int kbn = kb + 64;
            #pragma unroll
            for (int nt = 0; nt < 4; nt++) {
                const short* kp = Kh + (long)(kbn + nt * 16 + l15) * DK + q8;
                nk0[nt] = *(const short8*)(kp);
                nk1[nt] = *(const short8*)(kp + 32);
            }
        }

        // S-tile = (Q/8) K^T
        f32x4 sc[4];
        #pragma unroll
        for (int nt = 0; nt < 4; nt++) {
            f32x4 z = {};
            z = __builtin_amdgcn_mfma_f32_16x16x32_bf16(aq0, bk0[nt], z, 0, 0, 0);
            z = __builtin_amdgcn_mfma_f32_16x16x32_bf16(aq1, bk1[nt], z, 0, 0, 0);
            sc[nt] = z;
        }

        float pv[4][4];
        float mx[4] = {-1e30f, -1e30f, -1e30f, -1e30f};
        if (kb == qbase) {
            // diagonal chunk: fully inside band, skip mask arithmetic
            #pragma unroll
            for (int nt = 0; nt < 4; nt++)
                #pragma unroll
                for (int r = 0; r < 4; r++) {
                    pv[nt][r] = sc[nt][r];
                    mx[r] = fmaxf(mx[r], sc[nt][r]);
                }
        } else {
            #pragma unroll
            for (int nt = 0; nt < 4; nt++) {
                const int kg = kb + nt * 16 + l15;
                #pragma unroll
                for (int r = 0; r < 4; r++) {
                    const int qI = qbase + w * 16 + qg * 4 + r;
                    int dlt = qI - kg; if (dlt < 0) dlt = -dlt;
                    const float v = (dlt < BANDW) ? sc[nt][r] : -1e30f;
                    pv[nt][r] = v;
                    mx[r] = fmaxf(mx[r], v);
                }
            }
        }
        #pragma unroll
        for (int mk = 1; mk < 16; mk <<= 1)
            #pragma unroll
            for (int r = 0; r < 4; r++) mx[r] = fmaxf(mx[r], __shfl_xor(mx[r], mk, 64));

        float alpha[4], lnew[4];
        #pragma unroll
        for (int r = 0; r < 4; r++) {
            const float mn = fmaxf(m_r[r], mx[r]);
            alpha[r] = __builtin_exp2f((m_r[r] - mn) * 1.44269504f);
            m_r[r] = mn;
            lnew[r] = 0.f;
        }
        #pragma unroll
        for (int nt = 0; nt < 4; nt++)
            #pragma unroll
            for (int r = 0; r < 4; r++) {
                const float p = (pv[nt][r] > -0.5e30f)
                    ? __builtin_exp2f((pv[nt][r] - m_r[r]) * 1.44269504f) : 0.f;
                pv[nt][r] = p;
                lnew[r] += p;
            }
        #pragma unroll
        for (int mk = 1; mk < 16; mk <<= 1)
            #pragma unroll
            for (int r = 0; r < 4; r++) lnew[r] += __shfl_xor(lnew[r], mk, 64);
        #pragma unroll
        for (int r = 0; r < 4; r++) l_r[r] = l_r[r] * alpha[r] + lnew[r];
        #pragma unroll
        for (int nt2 = 0; nt2 < 4; nt2++)
            #pragma unroll
            for (int r = 0; r < 4; r++) o[nt2][r] *= alpha[r];

        // P (C layout) -> per-wave LDS -> A layout (lgkm wait only)
        #pragma unroll
        for (int nt = 0; nt < 4; nt++)
            #pragma unroll
            for (int r = 0; r < 4; r++)
                Pl[w][qg * 4 + r][nt * 16 + l15] = f2bf(pv[nt][r]);
        asm volatile("s_waitcnt lgkmcnt(0)" ::: "memory");
        const short8 ap0 = *(const short8*)(&Pl[w][l15][q8]);
        const short8 ap1 = *(const short8*)(&Pl[w][l15][32 + q8]);

        #pragma unroll
        for (int nt2 = 0; nt2 < 4; nt2++) {
            const short* vrow = &Vt[nt2 * 16 + l15][kloc];
            const short8 bv0 = *(const short8*)(vrow + q8);
            const short8 bv1 = *(const short8*)(vrow + 32 + q8);
            o[nt2] = __builtin_amdgcn_mfma_f32_16x16x32_bf16(ap0, bv0, o[nt2], 0, 0, 0);
            o[nt2] = __builtin_amdgcn_mfma_f32_16x16x32_bf16(ap1, bv1, o[nt2], 0, 0, 0);
        }
    }

    #pragma unroll
    for (int nt2 = 0; nt2 < 4; nt2++)
        #pragma unroll
        for (int r = 0; r < 4; r++) {
            const int qI = qbase + w * 16 + qg * 4 + r;
            const int d = nt2 * 16 + l15;
            g_AO[((long)b * S_LEN + qI) * 1024 + h * DK + d] = f2bf(o[nt2][r] / l_r[r]);
        }
}

extern "C" void kernel_launch(void* const* d_in, const int* in_sizes, int n_in,
                              void* d_out, int out_size, void* d_ws, size_t ws_size,
                              hipStream_t stream) {
    float* out = (float*)d_out;

    convert_all<<<(TOTC + 255) / 256, 256, 0, stream>>>(
        d_in[0], d_in[1], d_in[2], d_in[3], d_in[4], d_in[5], d_in[6], d_in[7], d_in[8]);
    qkv_gemm<<<dim3(32, 8, 3), 256, 0, stream>>>();
    attn_kernel<<<dim3(2 * NH * (S_LEN / 64)), 256, 0, stream>>>();
    o_gemm<<<dim3(32, 16), 256, 0, stream>>>(out);
}